// Round 1
// baseline (459.869 us; speedup 1.0000x reference)
//
#include <hip/hip_runtime.h>
#include <hip/hip_bf16.h>

// HashNGramEmbedding: out[b,i,:] = (1/6) * sum_{n=3..8} E_n[hash_n(b,i), :]
// hash_n = rolling polynomial hash (Horner) over window [i-n+1 .. i], mod 100000,
// except positions i < n-1 use the raw byte tokens[b,i].
//
// Layout: one 64-lane wave per position; lane handles 4 fp32 (float4) of EMBED=256.
// Gathers are 1KB fully-coalesced row reads. Hash chain is shared across n (the
// n+1-gram hash extends the n-gram hash by one Horner step).

#define HASH_BASE 257
#define VOCAB     100000
#define EMBED     256
#define SEQ       8192
#define SEQ_SHIFT 13      // log2(SEQ)
#define WAVES_PER_BLOCK 4

__global__ __launch_bounds__(64 * WAVES_PER_BLOCK) void hash_ngram_embed_kernel(
    const int* __restrict__ tokens,
    const float* __restrict__ E3, const float* __restrict__ E4,
    const float* __restrict__ E5, const float* __restrict__ E6,
    const float* __restrict__ E7, const float* __restrict__ E8,
    float* __restrict__ out, int total_pos)
{
    const int wave = threadIdx.x >> 6;
    const int lane = threadIdx.x & 63;
    const int pos  = blockIdx.x * WAVES_PER_BLOCK + wave;   // global (b*SEQ + i)
    if (pos >= total_pos) return;

    const int i = pos & (SEQ - 1);
    // tokens row base: pos - i == b*SEQ, so tokens + pos - i is row start; just index
    // absolute: tokens[pos - j] is valid within the row iff i - j >= 0.

    // Load the 8-byte window (wave-uniform addresses -> broadcast loads).
    int w[8];
#pragma unroll
    for (int j = 0; j < 8; ++j) {
        w[j] = (i - j >= 0) ? tokens[pos - j] : 0;
    }

    const int x = w[0];
    int h = x;
    int ids[6];
#pragma unroll
    for (int j = 1; j < 8; ++j) {
        h = (h * HASH_BASE + w[j]) % VOCAB;   // stays in [0, VOCAB), no overflow
        if (j >= 2) {
            const int n = j + 1;              // n-gram size this step completes
            ids[j - 2] = (i < n - 1) ? x : h; // raw byte for warm-up positions
        }
    }

    const float* tabs[6] = {E3, E4, E5, E6, E7, E8};
    const int off = lane * 4;

    float4 acc = make_float4(0.f, 0.f, 0.f, 0.f);
#pragma unroll
    for (int t = 0; t < 6; ++t) {
        const float4 v = *(const float4*)(tabs[t] + (size_t)ids[t] * EMBED + off);
        acc.x += v.x; acc.y += v.y; acc.z += v.z; acc.w += v.w;
    }

    const float scale = 1.0f / 6.0f;
    float4 r = make_float4(acc.x * scale, acc.y * scale, acc.z * scale, acc.w * scale);
    *(float4*)(out + (size_t)pos * EMBED + off) = r;
}

extern "C" void kernel_launch(void* const* d_in, const int* in_sizes, int n_in,
                              void* d_out, int out_size, void* d_ws, size_t ws_size,
                              hipStream_t stream)
{
    const int*   tokens = (const int*)d_in[0];
    const float* E3 = (const float*)d_in[1];
    const float* E4 = (const float*)d_in[2];
    const float* E5 = (const float*)d_in[3];
    const float* E6 = (const float*)d_in[4];
    const float* E7 = (const float*)d_in[5];
    const float* E8 = (const float*)d_in[6];
    float* out = (float*)d_out;

    const int total_pos = in_sizes[0];                  // B*S = 65536
    const int blocks = (total_pos + WAVES_PER_BLOCK - 1) / WAVES_PER_BLOCK;

    hash_ngram_embed_kernel<<<blocks, 64 * WAVES_PER_BLOCK, 0, stream>>>(
        tokens, E3, E4, E5, E6, E7, E8, out, total_pos);
}